// Round 10
// baseline (161.812 us; speedup 1.0000x reference)
//
#include <hip/hip_runtime.h>
#include <hip/hip_bf16.h>
#include <stdint.h>

// B=32768 queries, M=4096 memory rows, D=128.
//   logits = Q @ M^T ; attn = softmax(logits) ; out = attn @ M
// Flash-style fused kernel. bf16x3-split MFMA QK^T (near-fp32), bf16 PV.
// v10: phase-overlap via deep per-wave ILP. Rounds 6-9 plateaued at ~150us
// with MfmaUtil~40 + LDSpipe~42 + VALU~26 = ~100%: barrier lockstep ran the
// CU one pipe at a time. Fix: 1 block/CU (512-reg budget), full K/V register
// double-buffer (192 VGPR), tri-buffered LDS staged 2 tiles ahead. Each iter:
// QK(t)+PV(t-1) = 32 MFMAs issued with ZERO operand waits (regs loaded last
// iter), then READ(t+1) flies under softmax(t)'s VALU tail. No M-split, no
// merge: 256 blocks store normalized output directly.

typedef float   f32x16 __attribute__((ext_vector_type(16)));
typedef short   bf16x8 __attribute__((ext_vector_type(8)));
typedef uint32_t u32;

#define AS1 __attribute__((address_space(1)))
#define AS3 __attribute__((address_space(3)))

#define D_DIM 128
#define B_ROWS 32768
#define TILE_HW 12288     // halfwords per 32-row tile: [khi 4096|klo 4096|v 4096]
#define MT 128            // memory tiles

#if __has_builtin(__builtin_amdgcn_exp2f)
#define EXP2F(x) __builtin_amdgcn_exp2f(x)
#else
#define EXP2F(x) exp2f(x)
#endif

__device__ __forceinline__ uint16_t f32_to_bf16_rne(float x) {
    u32 u = __float_as_uint(x);
    u32 r = u + 0x7fffu + ((u >> 16) & 1u);
    return (uint16_t)(r >> 16);
}
__device__ __forceinline__ float bf16_to_f32(uint16_t h) {
    return __uint_as_float(((u32)h) << 16);
}

// ---------------------------------------------------------------------------
// Prep: memory -> interleaved fragment-linear bf16 tiles in d_ws.
// Per tile mt (24576 B): [0,8K) khi frags, [8K,16K) klo frags, [16K,24K) v frags.
// ---------------------------------------------------------------------------
__global__ void prep_frags(const float* __restrict__ mem,
                           uint16_t* __restrict__ kv) {
    int t = blockIdx.x * blockDim.x + threadIdx.x;  // 0..65535
    int lane = t & 63;
    int fi = t >> 6;                                // 0..1023
    int f8 = fi & 7, mt = fi >> 3;
    size_t base = (size_t)mt * TILE_HW;
    {   // K fragment (hi/lo split)
        int m  = mt * 32 + (lane & 31);
        int d0 = f8 * 16 + (lane >> 5) * 8;
        const float* src = mem + (size_t)m * D_DIM + d0;
        #pragma unroll
        for (int e = 0; e < 8; ++e) {
            float x = src[e];
            uint16_t hb = f32_to_bf16_rne(x);
            kv[base + f8 * 512 + lane * 8 + e] = hb;
            kv[base + 4096 + f8 * 512 + lane * 8 + e] =
                f32_to_bf16_rne(x - bf16_to_f32(hb));
        }
    }
    {   // V^T fragment (plain bf16)
        int dt = fi & 3, ks = (fi >> 2) & 1;
        int d  = dt * 32 + (lane & 31);
        int m0 = mt * 32 + ks * 16 + (lane >> 5) * 8;
        #pragma unroll
        for (int e = 0; e < 8; ++e)
            kv[base + 8192 + f8 * 512 + lane * 8 + e] =
                f32_to_bf16_rne(mem[(size_t)(m0 + e) * D_DIM + d]);
    }
}

// ---------------------------------------------------------------------------
// Main kernel: 256 blocks x 256 threads (4 waves, 1 block/CU, 1 wave/SIMD).
// LDS tri-buffered 24KB tiles (72 KB), staged 2 ahead; K/V register
// double-buffer (A/B), read 1 tile ahead.
// ---------------------------------------------------------------------------

#define STAGE(t_, wb_) do {                                                   \
    const char* g_ = (const char*)(kv + (size_t)(t_) * TILE_HW);              \
    char* l_ = (char*)&sbuf[wb_][0];                                          \
    _Pragma("unroll")                                                         \
    for (int j_ = 0; j_ < 6; ++j_) {                                          \
        int ch_ = wave * 6 + j_;                                              \
        __builtin_amdgcn_global_load_lds(                                     \
            (const AS1 char*)(g_ + ch_ * 1024 + lane * 16),                   \
            (AS3 char*)(l_ + ch_ * 1024), 16, 0, 0);                          \
    }                                                                         \
} while (0)

#define READKV(wb_, KH, KL, VF) do {                                          \
    const uint16_t* b_ = &sbuf[wb_][0] + lane * 8;                            \
    _Pragma("unroll")                                                         \
    for (int kk_ = 0; kk_ < 8; ++kk_) {                                       \
        KH[kk_] = *(const bf16x8*)(b_ + kk_ * 512);                           \
        KL[kk_] = *(const bf16x8*)(b_ + 4096 + kk_ * 512);                    \
        VF[kk_] = *(const bf16x8*)(b_ + 8192 + kk_ * 512);                    \
    }                                                                         \
} while (0)

#define MFMA_BF16(a_, b_, c_) __builtin_amdgcn_mfma_f32_32x32x16_bf16(a_, b_, c_, 0, 0, 0)

// QK^T (bf16x3 split, 2 chains) on resident registers -> sh, sl.
#define QKI(KH, KL) do {                                                      \
    _Pragma("unroll")                                                         \
    for (int i_ = 0; i_ < 16; ++i_) { sh[i_] = 0.f; sl[i_] = 0.f; }           \
    _Pragma("unroll")                                                         \
    for (int kk_ = 0; kk_ < 8; ++kk_) {                                       \
        sh = MFMA_BF16(KH[kk_], qhi[kk_], sh);                                \
        sl = MFMA_BF16(KH[kk_], qlo[kk_], sl);                                \
        sl = MFMA_BF16(KL[kk_], qhi[kk_], sl);                                \
    }                                                                         \
} while (0)

// PV for the previous tile: resident V frags + pf0/pf1 from last softmax.
#define PVI(VF) do {                                                          \
    O0 = MFMA_BF16(VF[0], pf0, O0);                                           \
    O1 = MFMA_BF16(VF[1], pf0, O1);                                           \
    O2 = MFMA_BF16(VF[2], pf0, O2);                                           \
    O3 = MFMA_BF16(VF[3], pf0, O3);                                           \
    O0 = MFMA_BF16(VF[4], pf1, O0);                                           \
    O1 = MFMA_BF16(VF[5], pf1, O1);                                           \
    O2 = MFMA_BF16(VF[6], pf1, O2);                                           \
    O3 = MFMA_BF16(VF[7], pf1, O3);                                           \
} while (0)

// Online softmax on sh+sl (Sᵀ layout: q = lane&31) -> m_run/l_run/O-rescale,
// and pf0/pf1 bf16 B-frags for the NEXT iteration's PV.
#define SMX() do {                                                            \
    f32x16 s_ = sh + sl;                                                      \
    float a0=fmaxf(s_[0],s_[1]),  a1=fmaxf(s_[2],s_[3]);                      \
    float a2=fmaxf(s_[4],s_[5]),  a3=fmaxf(s_[6],s_[7]);                      \
    float a4=fmaxf(s_[8],s_[9]),  a5=fmaxf(s_[10],s_[11]);                    \
    float a6=fmaxf(s_[12],s_[13]),a7=fmaxf(s_[14],s_[15]);                    \
    float tmax = fmaxf(fmaxf(fmaxf(a0,a1),fmaxf(a2,a3)),                      \
                       fmaxf(fmaxf(a4,a5),fmaxf(a6,a7)));                     \
    tmax = fmaxf(tmax, __shfl_xor(tmax, 32));                                 \
    if (__any(tmax > m_run + 8.0f)) {     /* defer-max (T13) */               \
        float mn = fmaxf(m_run, tmax);                                        \
        float fr = EXP2F(m_run - mn);                                         \
        m_run = mn; l_run *= fr;                                              \
        _Pragma("unroll")                                                     \
        for (int r_ = 0; r_ < 16; ++r_) {                                     \
            O0[r_] *= fr; O1[r_] *= fr; O2[r_] *= fr; O3[r_] *= fr;           \
        }                                                                     \
    }                                                                         \
    _Pragma("unroll")                                                         \
    for (int r_ = 0; r_ < 16; ++r_) s_[r_] = EXP2F(s_[r_] - m_run);           \
    { float q0s=s_[0]+s_[1],  q1s=s_[2]+s_[3],  q2s=s_[4]+s_[5],  q3s=s_[6]+s_[7];   \
      float q4s=s_[8]+s_[9],  q5s=s_[10]+s_[11],q6s=s_[12]+s_[13],q7s=s_[14]+s_[15]; \
      l_run += ((q0s+q1s)+(q2s+q3s)) + ((q4s+q5s)+(q6s+q7s)); }               \
    u32 c_[8];                                                                \
    _Pragma("unroll")                                                         \
    for (int j_ = 0; j_ < 8; ++j_)                                            \
        asm("v_cvt_pk_bf16_f32 %0, %1, %2"                                    \
            : "=v"(c_[j_]) : "v"(s_[2*j_]), "v"(s_[2*j_+1]));                 \
    asm("v_permlane32_swap_b32 %0, %1" : "+v"(c_[0]), "+v"(c_[2]));           \
    asm("v_permlane32_swap_b32 %0, %1" : "+v"(c_[1]), "+v"(c_[3]));           \
    asm("v_permlane32_swap_b32 %0, %1" : "+v"(c_[4]), "+v"(c_[6]));           \
    asm("v_permlane32_swap_b32 %0, %1" : "+v"(c_[5]), "+v"(c_[7]));           \
    { u32 w_[4] = {c_[0], c_[1], c_[2], c_[3]}; __builtin_memcpy(&pf0, w_, 16); } \
    { u32 w_[4] = {c_[4], c_[5], c_[6], c_[7]}; __builtin_memcpy(&pf1, w_, 16); } \
} while (0)

#define STORE_TILE(Ot_, t_) do {                                              \
    _Pragma("unroll")                                                         \
    for (int g_ = 0; g_ < 4; ++g_) {                                          \
        float4 v_;                                                            \
        v_.x = Ot_[4*g_+0] * rinv;                                            \
        v_.y = Ot_[4*g_+1] * rinv;                                            \
        v_.z = Ot_[4*g_+2] * rinv;                                            \
        v_.w = Ot_[4*g_+3] * rinv;                                            \
        int d_ = (t_) * 32 + 8 * g_ + 4 * hi32;                               \
        *(float4*)(orow + d_) = v_;                                           \
    }                                                                         \
} while (0)

__global__ __launch_bounds__(256, 1)
void attn_main(const float* __restrict__ qin,
               const uint16_t* __restrict__ kv,
               float* __restrict__ out) {
    __shared__ uint16_t sbuf[3][TILE_HW];   // 3 x 24 KB = 72 KB

    const int lane = threadIdx.x & 63;
    const int wave = threadIdx.x >> 6;
    const int q0   = blockIdx.x * 128 + wave * 32;
    const int qrow = q0 + (lane & 31);
    const int hi32 = lane >> 5;

    // Q prep: scale by log2(e), split into bf16 hi/lo (B-frag of Sᵀ MFMA).
    bf16x8 qhi[8], qlo[8];
    {
        const float LOG2E = 1.44269504088896340736f;
        #pragma unroll
        for (int kk = 0; kk < 8; ++kk) {
            const float* src = qin + (size_t)qrow * D_DIM + kk * 16 + hi32 * 8;
            float4 a = *(const float4*)(src);
            float4 b = *(const float4*)(src + 4);
            float xs[8] = {a.x, a.y, a.z, a.w, b.x, b.y, b.z, b.w};
            #pragma unroll
            for (int e = 0; e < 8; ++e) {
                float x = xs[e] * LOG2E;
                uint16_t hb = f32_to_bf16_rne(x);
                qhi[kk][e] = (short)hb;
                qlo[kk][e] = (short)f32_to_bf16_rne(x - bf16_to_f32(hb));
            }
        }
    }

    f32x16 O0, O1, O2, O3;
    #pragma unroll
    for (int i = 0; i < 16; ++i) { O0[i]=0.f; O1[i]=0.f; O2[i]=0.f; O3[i]=0.f; }
    float m_run = -1e30f, l_run = 0.f;

    bf16x8 khA[8], klA[8], vfA[8], khB[8], klB[8], vfB[8];
    f32x16 sh, sl;
    bf16x8 pf0, pf1;

    // Prologue: stage tiles 0,1; read tile 0 into A.
    STAGE(0, 0);
    STAGE(1, 1);
    __syncthreads();
    READKV(0, khA, klA, vfA);

    // t = 0: QK(0), read tile 1 -> B, softmax(0) -> pf. (No PV yet.)
    STAGE(2, 2);
    QKI(khA, klA);
    READKV(1, khB, klB, vfB);
    SMX();
    __syncthreads();

    // Steady state: t = 1..126 in pairs. Iter t: QK(t) + PV(t-1) burst
    // (all operands register-resident), READ(t+1), softmax(t), barrier.
    #pragma unroll 1
    for (int tp = 0; tp < 63; ++tp) {
        const int t = 2 * tp + 1;
        // --- half 1: current tile t in B ---
        if (t + 2 < MT) STAGE(t + 2, (t + 2) % 3);
        QKI(khB, klB);
        PVI(vfA);                            // tile t-1
        READKV((t + 1) % 3, khA, klA, vfA);  // tile t+1
        SMX();                               // tile t -> pf
        __syncthreads();
        // --- half 2: current tile t+1 in A ---
        if (t + 3 < MT) STAGE(t + 3, (t + 3) % 3);
        QKI(khA, klA);
        PVI(vfB);                            // tile t
        READKV((t + 2) % 3, khB, klB, vfB);  // tile t+2
        SMX();                               // tile t+1 -> pf
        __syncthreads();
    }

    // Tail: t = 127 in B (read during tp=62 half 2).
    QKI(khB, klB);
    PVI(vfA);       // tile 126
    SMX();          // tile 127 -> pf
    PVI(vfB);       // tile 127

    // Epilogue: combine pair-lane partial sums, normalize, store direct.
    l_run += __shfl_xor(l_run, 32);
    float rinv = 1.0f / l_run;
    float* orow = out + (size_t)qrow * D_DIM;
    STORE_TILE(O0, 0);
    STORE_TILE(O1, 1);
    STORE_TILE(O2, 2);
    STORE_TILE(O3, 3);
}

extern "C" void kernel_launch(void* const* d_in, const int* in_sizes, int n_in,
                              void* d_out, int out_size, void* d_ws, size_t ws_size,
                              hipStream_t stream) {
    const float* local_stats = (const float*)d_in[0];   // [32768,128] f32
    const float* memory      = (const float*)d_in[1];   // [4096,128]  f32
    float* out = (float*)d_out;                         // [32768,128] f32

    uint16_t* kv = (uint16_t*)d_ws;   // 128 tiles x 24576 B = 3 MB

    prep_frags<<<256, 256, 0, stream>>>(memory, kv);
    attn_main<<<256, 256, 0, stream>>>(local_stats, kv, out);
}